// Round 1
// baseline (247.479 us; speedup 1.0000x reference)
//
#include <hip/hip_runtime.h>

// PointTransformerLayer fused kernel for MI355X (gfx950).
// B=2,T=16 -> BT=32; N=128 points; DIM=64; pos-feat 34 (pad->64); ATTN_HID=256.
// Pipeline per (bt,i) workgroup (256 thr = 4 waves):
//   X1[j][34] = p_i - p_j                  (LDS, bf16 hi/lo, swizzled)
//   H1 = relu(W1 @ X1^T + b1)              (MFMA, -> LDS)
//   E  = W2 @ H1^T + b2                    (MFMA, stays in C-frags)
//   U  = q_i - k_j + E  (->LDS), Vp = v_j + E (registers)
//   H2c = relu(A1c @ U^T + b1c) per 64-chunk (-> LDS), S += A2c @ H2c^T
//   softmax over j per (d) + weighted sum of Vp   (register epilogue)
// All GEMMs hi/lo-split bf16 (3 MFMAs / product) => ~f32 accuracy.
// ws layout: qkv f32 [32][128][192] @0 (3145728 B); wT f32 @3145728 (49152 B);
//   frag buffers (bf16 hi plane then lo plane): fW1@3194880, fW2@3211264,
//   fA1@3227648, fA2@3293184; total 3358720 B.

typedef short short8 __attribute__((ext_vector_type(8)));
typedef float f32x4 __attribute__((ext_vector_type(4)));
typedef unsigned int u32x2 __attribute__((ext_vector_type(2)));

__device__ __forceinline__ unsigned short f2bf(float x) {
  union { float f; unsigned int u; } a; a.f = x;
  unsigned int r = a.u + 0x7fffu + ((a.u >> 16) & 1u);  // RN-even
  return (unsigned short)(r >> 16);
}
__device__ __forceinline__ float bf2f(unsigned short h) {
  union { unsigned int u; float f; } a; a.u = ((unsigned int)h) << 16; return a.f;
}

// ---------------- prep: weight transpose + MFMA A-fragment buffers ----------------
// A-frag layout (16x16x32): lane l holds A[row = mt*16 + (l&15)][k = kc*32 + (l>>4)*8 + e]
// stored frag-linear: idx = ((mt*KC + kc)*64 + lane)*8 + e ; hi plane then lo plane.
__device__ __forceinline__ void fill_frag(unsigned short* dst, int plane,
    const float* src, int Ksrc, int KC, int idx) {
  int e = idx & 7;
  int lane = (idx >> 3) & 63;
  int kc = (idx >> 9) % KC;
  int mt = idx / (512 * KC);
  int row = mt * 16 + (lane & 15);
  int k = kc * 32 + ((lane >> 4) << 3) + e;
  float v = (k < Ksrc) ? src[row * Ksrc + k] : 0.0f;
  unsigned short hi = f2bf(v);
  unsigned short lo = f2bf(v - bf2f(hi));
  dst[idx] = hi;
  dst[plane + idx] = lo;
}

__global__ void prep_kernel(const float* __restrict__ wqkv,
    const float* __restrict__ pw1, const float* __restrict__ pw2,
    const float* __restrict__ aw1, const float* __restrict__ aw2,
    float* __restrict__ wT, unsigned short* __restrict__ fW1,
    unsigned short* __restrict__ fW2, unsigned short* __restrict__ fA1,
    unsigned short* __restrict__ fA2) {
  int gid = blockIdx.x * 256 + threadIdx.x;
  if (gid < 12288) {  // wT[k][c] = w_qkv[c][k]
    int k = gid / 192, c = gid % 192;
    wT[gid] = wqkv[c * 64 + k];
    return;
  }
  gid -= 12288;
  if (gid < 4096) { fill_frag(fW1, 4096, pw1, 34, 2, gid); return; }   // pm_w1 [64][34->64]
  gid -= 4096;
  if (gid < 4096) { fill_frag(fW2, 4096, pw2, 64, 2, gid); return; }   // pm_w2 [64][64]
  gid -= 4096;
  if (gid < 16384) { fill_frag(fA1, 16384, aw1, 64, 2, gid); return; } // am_w1 [256][64]
  gid -= 16384;
  if (gid < 16384) { fill_frag(fA2, 16384, aw2, 256, 8, gid); return; }// am_w2 [64][256]
}

// ---------------- qkv = x @ w_qkv^T (f32) ----------------
__global__ void qkv_kernel(const float* __restrict__ x, const float* __restrict__ wT,
                           float* __restrict__ qkv) {
  __shared__ float xs[64];
  int row = blockIdx.x;           // bt*128 + n
  int tid = threadIdx.x;          // 0..191 = output channel
  if (tid < 64) xs[tid] = x[row * 64 + tid];
  __syncthreads();
  float acc = 0.f;
#pragma unroll
  for (int k = 0; k < 64; ++k) acc += xs[k] * wT[k * 192 + tid];
  qkv[row * 192 + tid] = acc;
}

// ---------------- main fused kernel ----------------
#define LP 16384  // LDS plane size (hi vs lo)

__global__ __launch_bounds__(256, 2) void main_kernel(
    const float* __restrict__ pos, const float* __restrict__ qkv,
    const unsigned short* __restrict__ fW1, const unsigned short* __restrict__ fW2,
    const unsigned short* __restrict__ fA1, const unsigned short* __restrict__ fA2,
    const float* __restrict__ pb1, const float* __restrict__ pb2,
    const float* __restrict__ ab1, const float* __restrict__ ab2,
    float* __restrict__ out) {
  __shared__ char bufA[32768];  // X1 then U   : [128 j][64 k] bf16, hi/lo planes, swizzled
  __shared__ char bufB[32768];  // H1 then H2c : same layout
  const int i = blockIdx.x, bt = blockIdx.y;
  const int tid = threadIdx.x;
  const int w = tid >> 6, l = tid & 63, lr = l & 15, lg = l >> 4;
  const int swz = (lr & 7) << 4;         // row-XOR swizzle (j&7 == lr&7 for all tiles)
  const int kbase = lg * 16;             // byte offset of this lane's k-group in a 128B row
  const int wrow = w * 32 + lg * 8;      // byte offset of this lane's C-column group

  // zero bufA (covers k=34..63 pad of X1)
  f32x4 zero = {0.f, 0.f, 0.f, 0.f};
#pragma unroll
  for (int o = 0; o < 8; ++o) *(f32x4*)(bufA + tid * 16 + o * 4096) = zero;
  __syncthreads();

  // X1[j][f] = p[bt,i,f] - p[bt,j,f],  f = c*17 + jj,  34*128 = 17*256 elems
  for (int it = 0; it < 17; ++it) {
    int idx = tid + it * 256;
    int f = idx >> 7, j = idx & 127;
    int c = (f >= 17) ? 1 : 0;
    int jj = f - 17 * c;
    const float* ps = pos + (((bt * 17 + jj) * 3 + c) << 7);
    float val = ps[i] - ps[j];
    unsigned short hi = f2bf(val);
    unsigned short lo = f2bf(val - bf2f(hi));
    int off = j * 128 + ((2 * f) ^ ((j & 7) << 4));
    *(unsigned short*)(bufA + off) = hi;
    *(unsigned short*)(bufA + LP + off) = lo;
  }
  __syncthreads();

  f32x4 acc[8], acc4[8], vp[8];

  // ---- G1: H1^T[h][j] = relu(W1 @ X1^T + b1), wave w owns h-tile w ----
  {
    f32x4 bias = *(const f32x4*)(pb1 + w * 16 + lg * 4);
#pragma unroll
    for (int t = 0; t < 8; ++t) acc[t] = bias;
#pragma unroll
    for (int kc = 0; kc < 2; ++kc) {
      const unsigned short* ap = fW1 + ((w * 2 + kc) * 64 + l) * 8;
      short8 aHi = *(const short8*)(ap);
      short8 aLo = *(const short8*)(ap + 4096);
      int kb = kc * 64 + kbase;
#pragma unroll
      for (int t = 0; t < 8; ++t) {
        int off = (t * 16 + lr) * 128 + (kb ^ swz);
        short8 bHi = *(const short8*)(bufA + off);
        short8 bLo = *(const short8*)(bufA + LP + off);
        acc[t] = __builtin_amdgcn_mfma_f32_16x16x32_bf16(aHi, bHi, acc[t], 0, 0, 0);
        acc[t] = __builtin_amdgcn_mfma_f32_16x16x32_bf16(aHi, bLo, acc[t], 0, 0, 0);
        acc[t] = __builtin_amdgcn_mfma_f32_16x16x32_bf16(aLo, bHi, acc[t], 0, 0, 0);
      }
    }
#pragma unroll
    for (int t = 0; t < 8; ++t) {  // relu + hi/lo pack -> H1[j][h]
      float v0 = fmaxf(acc[t][0], 0.f), v1 = fmaxf(acc[t][1], 0.f);
      float v2 = fmaxf(acc[t][2], 0.f), v3 = fmaxf(acc[t][3], 0.f);
      unsigned short h0 = f2bf(v0), h1 = f2bf(v1), h2 = f2bf(v2), h3 = f2bf(v3);
      unsigned short g0 = f2bf(v0 - bf2f(h0)), g1 = f2bf(v1 - bf2f(h1));
      unsigned short g2 = f2bf(v2 - bf2f(h2)), g3 = f2bf(v3 - bf2f(h3));
      u32x2 hi, lo;
      hi[0] = (unsigned)h0 | ((unsigned)h1 << 16); hi[1] = (unsigned)h2 | ((unsigned)h3 << 16);
      lo[0] = (unsigned)g0 | ((unsigned)g1 << 16); lo[1] = (unsigned)g2 | ((unsigned)g3 << 16);
      int off = (t * 16 + lr) * 128 + (wrow ^ swz);
      *(u32x2*)(bufB + off) = hi;
      *(u32x2*)(bufB + LP + off) = lo;
    }
  }
  __syncthreads();

  // ---- G2: E^T[d][j] = W2 @ H1^T + b2 ----
  {
    f32x4 bias = *(const f32x4*)(pb2 + w * 16 + lg * 4);
#pragma unroll
    for (int t = 0; t < 8; ++t) acc[t] = bias;
#pragma unroll
    for (int kc = 0; kc < 2; ++kc) {
      const unsigned short* ap = fW2 + ((w * 2 + kc) * 64 + l) * 8;
      short8 aHi = *(const short8*)(ap);
      short8 aLo = *(const short8*)(ap + 4096);
      int kb = kc * 64 + kbase;
#pragma unroll
      for (int t = 0; t < 8; ++t) {
        int off = (t * 16 + lr) * 128 + (kb ^ swz);
        short8 bHi = *(const short8*)(bufB + off);
        short8 bLo = *(const short8*)(bufB + LP + off);
        acc[t] = __builtin_amdgcn_mfma_f32_16x16x32_bf16(aHi, bHi, acc[t], 0, 0, 0);
        acc[t] = __builtin_amdgcn_mfma_f32_16x16x32_bf16(aHi, bLo, acc[t], 0, 0, 0);
        acc[t] = __builtin_amdgcn_mfma_f32_16x16x32_bf16(aLo, bHi, acc[t], 0, 0, 0);
      }
    }
  }
  // ---- E-stage: U = q_i - k_j + E (->bufA), Vp = v_j + E (regs). bufA(X1) is dead. ----
  {
    const float* qb = qkv + (bt * 128 + i) * 192 + w * 16 + lg * 4;
    f32x4 q4 = *(const f32x4*)qb;
#pragma unroll
    for (int t = 0; t < 8; ++t) {
      int j = t * 16 + lr;
      const float* kvb = qkv + (bt * 128 + j) * 192 + w * 16 + lg * 4;
      f32x4 k4 = *(const f32x4*)(kvb + 64);
      f32x4 v4 = *(const f32x4*)(kvb + 128);
      f32x4 e = acc[t];
      vp[t] = v4 + e;
      f32x4 u = q4 - k4 + e;
      unsigned short h0 = f2bf(u[0]), h1 = f2bf(u[1]), h2 = f2bf(u[2]), h3 = f2bf(u[3]);
      unsigned short g0 = f2bf(u[0] - bf2f(h0)), g1 = f2bf(u[1] - bf2f(h1));
      unsigned short g2 = f2bf(u[2] - bf2f(h2)), g3 = f2bf(u[3] - bf2f(h3));
      u32x2 hi, lo;
      hi[0] = (unsigned)h0 | ((unsigned)h1 << 16); hi[1] = (unsigned)h2 | ((unsigned)h3 << 16);
      lo[0] = (unsigned)g0 | ((unsigned)g1 << 16); lo[1] = (unsigned)g2 | ((unsigned)g3 << 16);
      int off = j * 128 + (wrow ^ swz);
      *(u32x2*)(bufA + off) = hi;
      *(u32x2*)(bufA + LP + off) = lo;
    }
  }
  __syncthreads();

  // ---- G3/G4 interleaved over 4 h-chunks of 64; acc4 = S^T[d][j] ----
  {
    f32x4 b4 = *(const f32x4*)(ab2 + w * 16 + lg * 4);
#pragma unroll
    for (int t = 0; t < 8; ++t) acc4[t] = b4;
  }
  for (int hc = 0; hc < 4; ++hc) {
    {  // G3 chunk: H2c^T[hlocal][j] = relu(A1c @ U^T + b1c)
      f32x4 b3 = *(const f32x4*)(ab1 + hc * 64 + w * 16 + lg * 4);
#pragma unroll
      for (int t = 0; t < 8; ++t) acc[t] = b3;
#pragma unroll
      for (int kc = 0; kc < 2; ++kc) {
        const unsigned short* ap = fA1 + (((hc * 4 + w) * 2 + kc) * 64 + l) * 8;
        short8 aHi = *(const short8*)(ap);
        short8 aLo = *(const short8*)(ap + 16384);
        int kb = kc * 64 + kbase;
#pragma unroll
        for (int t = 0; t < 8; ++t) {
          int off = (t * 16 + lr) * 128 + (kb ^ swz);
          short8 bHi = *(const short8*)(bufA + off);
          short8 bLo = *(const short8*)(bufA + LP + off);
          acc[t] = __builtin_amdgcn_mfma_f32_16x16x32_bf16(aHi, bHi, acc[t], 0, 0, 0);
          acc[t] = __builtin_amdgcn_mfma_f32_16x16x32_bf16(aHi, bLo, acc[t], 0, 0, 0);
          acc[t] = __builtin_amdgcn_mfma_f32_16x16x32_bf16(aLo, bHi, acc[t], 0, 0, 0);
        }
      }
#pragma unroll
      for (int t = 0; t < 8; ++t) {  // relu + pack -> H2c[j][hlocal]
        float v0 = fmaxf(acc[t][0], 0.f), v1 = fmaxf(acc[t][1], 0.f);
        float v2 = fmaxf(acc[t][2], 0.f), v3 = fmaxf(acc[t][3], 0.f);
        unsigned short h0 = f2bf(v0), h1 = f2bf(v1), h2 = f2bf(v2), h3 = f2bf(v3);
        unsigned short g0 = f2bf(v0 - bf2f(h0)), g1 = f2bf(v1 - bf2f(h1));
        unsigned short g2 = f2bf(v2 - bf2f(h2)), g3 = f2bf(v3 - bf2f(h3));
        u32x2 hi, lo;
        hi[0] = (unsigned)h0 | ((unsigned)h1 << 16); hi[1] = (unsigned)h2 | ((unsigned)h3 << 16);
        lo[0] = (unsigned)g0 | ((unsigned)g1 << 16); lo[1] = (unsigned)g2 | ((unsigned)g3 << 16);
        int off = (t * 16 + lr) * 128 + (wrow ^ swz);
        *(u32x2*)(bufB + off) = hi;
        *(u32x2*)(bufB + LP + off) = lo;
      }
    }
    __syncthreads();
#pragma unroll
    for (int kc2 = 0; kc2 < 2; ++kc2) {  // G4 partial: S^T += A2c @ H2c^T
      const unsigned short* ap = fA2 + ((w * 8 + hc * 2 + kc2) * 64 + l) * 8;
      short8 aHi = *(const short8*)(ap);
      short8 aLo = *(const short8*)(ap + 16384);
      int kb = kc2 * 64 + kbase;
#pragma unroll
      for (int t = 0; t < 8; ++t) {
        int off = (t * 16 + lr) * 128 + (kb ^ swz);
        short8 bHi = *(const short8*)(bufB + off);
        short8 bLo = *(const short8*)(bufB + LP + off);
        acc4[t] = __builtin_amdgcn_mfma_f32_16x16x32_bf16(aHi, bHi, acc4[t], 0, 0, 0);
        acc4[t] = __builtin_amdgcn_mfma_f32_16x16x32_bf16(aHi, bLo, acc4[t], 0, 0, 0);
        acc4[t] = __builtin_amdgcn_mfma_f32_16x16x32_bf16(aLo, bHi, acc4[t], 0, 0, 0);
      }
    }
    __syncthreads();
  }

  // ---- epilogue: softmax over j (8 tiles in-lane x 16 lanes), agg = sum attn*Vp ----
  f32x4 mx = acc4[0];
#pragma unroll
  for (int t = 1; t < 8; ++t) {
#pragma unroll
    for (int c = 0; c < 4; ++c) mx[c] = fmaxf(mx[c], acc4[t][c]);
  }
#pragma unroll
  for (int mask = 1; mask <= 8; mask <<= 1) {
#pragma unroll
    for (int c = 0; c < 4; ++c) mx[c] = fmaxf(mx[c], __shfl_xor(mx[c], mask));
  }
  f32x4 pd = zero, pn = zero;
#pragma unroll
  for (int t = 0; t < 8; ++t) {
#pragma unroll
    for (int c = 0; c < 4; ++c) {
      float e = __expf(acc4[t][c] - mx[c]);
      pd[c] += e;
      pn[c] += e * vp[t][c];
    }
  }
#pragma unroll
  for (int mask = 1; mask <= 8; mask <<= 1) {
#pragma unroll
    for (int c = 0; c < 4; ++c) {
      pd[c] += __shfl_xor(pd[c], mask);
      pn[c] += __shfl_xor(pn[c], mask);
    }
  }
  if (lr == 0) {
    f32x4 r;
#pragma unroll
    for (int c = 0; c < 4; ++c) r[c] = pn[c] / pd[c];
    *(f32x4*)(out + (bt * 128 + i) * 64 + w * 16 + lg * 4) = r;
  }
}

extern "C" void kernel_launch(void* const* d_in, const int* in_sizes, int n_in,
                              void* d_out, int out_size, void* d_ws, size_t ws_size,
                              hipStream_t stream) {
  const float* x    = (const float*)d_in[0];
  const float* pos  = (const float*)d_in[1];
  const float* wqkv = (const float*)d_in[2];
  const float* pw1  = (const float*)d_in[3];
  const float* pb1  = (const float*)d_in[4];
  const float* pw2  = (const float*)d_in[5];
  const float* pb2  = (const float*)d_in[6];
  const float* aw1  = (const float*)d_in[7];
  const float* ab1  = (const float*)d_in[8];
  const float* aw2  = (const float*)d_in[9];
  const float* ab2  = (const float*)d_in[10];
  float* out = (float*)d_out;
  char* ws = (char*)d_ws;

  float* qkv = (float*)ws;                              // 3145728 B
  float* wT  = (float*)(ws + 3145728);                  // 49152 B
  unsigned short* fW1 = (unsigned short*)(ws + 3194880);// 16384 B
  unsigned short* fW2 = (unsigned short*)(ws + 3211264);// 16384 B
  unsigned short* fA1 = (unsigned short*)(ws + 3227648);// 65536 B
  unsigned short* fA2 = (unsigned short*)(ws + 3293184);// 65536 B (total 3358720 B)

  hipLaunchKernelGGL(prep_kernel, dim3(208), dim3(256), 0, stream,
                     wqkv, pw1, pw2, aw1, aw2, wT, fW1, fW2, fA1, fA2);
  hipLaunchKernelGGL(qkv_kernel, dim3(4096), dim3(192), 0, stream, x, wT, qkv);
  hipLaunchKernelGGL(main_kernel, dim3(128, 32), dim3(256), 0, stream,
                     pos, qkv, fW1, fW2, fA1, fA2, pb1, pb2, ab1, ab2, out);
}

// Round 2
// 233.834 us; speedup vs baseline: 1.0584x; 1.0584x over previous
//
#include <hip/hip_runtime.h>

// PointTransformerLayer fused kernel for MI355X (gfx950) — round 2.
// 32x32x16 bf16 MFMA; weights hi/lo split (2 MFMA/product), activations single bf16.
// Per (bt,i) workgroup (256 thr = 4 waves, wave grid 2M x 2N):
//   X1[j][34->64] = p_i - p_j          (LDS bufA, bf16, XOR-swizzled)
//   H1 = relu(W1 @ X1^T + b1)          -> bufB
//   E  = W2 @ H1^T + b2                (stays in C-frags)
//   U  = q_i - k_j + E -> bufA ; Vp = v_j + E (regs)
//   per hc(4): H2c = relu(A1c @ U^T + b1c) -> bufB ; S += A2c @ H2c^T
//   softmax over j (no max-sub; exp-safe) + weighted Vp sum, cross-wave via LDS.
// ws layout: qkv f32 @0 (3145728 B); wT @3145728 (49152 B); frag buffers
//   (hi plane then lo plane): fW1@3194880, fW2@3211264, fA1@3227648, fA2@3293184.

typedef short short8 __attribute__((ext_vector_type(8)));
typedef float f32x4 __attribute__((ext_vector_type(4)));
typedef float f32x16 __attribute__((ext_vector_type(16)));
typedef unsigned int u32x2 __attribute__((ext_vector_type(2)));

__device__ __forceinline__ unsigned short f2bf(float x) {
  union { float f; unsigned int u; } a; a.f = x;
  unsigned int r = a.u + 0x7fffu + ((a.u >> 16) & 1u);  // RNE
  return (unsigned short)(r >> 16);
}
__device__ __forceinline__ float bf2f(unsigned short h) {
  union { unsigned int u; float f; } a; a.u = ((unsigned int)h) << 16; return a.f;
}
__device__ __forceinline__ unsigned int pk2(float a, float b) {  // b->hi, a->lo
  unsigned int r;
  asm("v_cvt_pk_bf16_f32 %0, %1, %2" : "=v"(r) : "v"(a), "v"(b));
  return r;
}

// ---------------- prep: weight transpose + 32x32x16 A-fragment buffers ----------------
// A-frag: lane l holds A[row = mt*32 + (l&31)][k = kc*16 + (l>>5)*8 + e], e=0..7.
// linear: idx = ((mt*KC + kc)*64 + lane)*8 + e ; hi plane then lo plane.
__device__ __forceinline__ void fill_frag(unsigned short* dst, int plane,
    const float* src, int Ksrc, int KC, int idx) {
  int e = idx & 7;
  int lane = (idx >> 3) & 63;
  int kc = (idx >> 9) % KC;
  int mt = idx / (512 * KC);
  int row = mt * 32 + (lane & 31);
  int k = kc * 16 + ((lane >> 5) << 3) + e;
  float v = (k < Ksrc) ? src[row * Ksrc + k] : 0.0f;
  unsigned short hi = f2bf(v);
  unsigned short lo = f2bf(v - bf2f(hi));
  dst[idx] = hi;
  dst[plane + idx] = lo;
}

__global__ void prep_kernel(const float* __restrict__ wqkv,
    const float* __restrict__ pw1, const float* __restrict__ pw2,
    const float* __restrict__ aw1, const float* __restrict__ aw2,
    float* __restrict__ wT, unsigned short* __restrict__ fW1,
    unsigned short* __restrict__ fW2, unsigned short* __restrict__ fA1,
    unsigned short* __restrict__ fA2) {
  int gid = blockIdx.x * 256 + threadIdx.x;
  if (gid < 12288) {  // wT[k][c] = w_qkv[c][k]
    int k = gid / 192, c = gid % 192;
    wT[gid] = wqkv[c * 64 + k];
    return;
  }
  gid -= 12288;
  if (gid < 4096) { fill_frag(fW1, 4096, pw1, 34, 4, gid); return; }   // [64][34->64]
  gid -= 4096;
  if (gid < 4096) { fill_frag(fW2, 4096, pw2, 64, 4, gid); return; }   // [64][64]
  gid -= 4096;
  if (gid < 16384) { fill_frag(fA1, 16384, aw1, 64, 4, gid); return; } // [256][64]
  gid -= 16384;
  if (gid < 16384) { fill_frag(fA2, 16384, aw2, 256, 16, gid); return; }// [64][256]
}

// ---------------- qkv = x @ w_qkv^T (f32) ----------------
__global__ void qkv_kernel(const float* __restrict__ x, const float* __restrict__ wT,
                           float* __restrict__ qkv) {
  __shared__ float xs[64];
  int row = blockIdx.x;           // bt*128 + n
  int tid = threadIdx.x;          // 0..191 = output channel
  if (tid < 64) xs[tid] = x[row * 64 + tid];
  __syncthreads();
  float acc = 0.f;
#pragma unroll
  for (int k = 0; k < 64; ++k) acc += xs[k] * wT[k * 192 + tid];
  qkv[row * 192 + tid] = acc;
}

// ---------------- main fused kernel ----------------
// C/D layout 32x32: col = l&31, row = (reg&3) + 8*(reg>>2) + 4*(l>>5).
__device__ __forceinline__ f32x16 ld16(const float* p, int l) {
  f32x16 r;
#pragma unroll
  for (int q = 0; q < 4; ++q) {
    f32x4 v = *(const f32x4*)(p + 8 * q + ((l >> 5) << 2));
#pragma unroll
    for (int s = 0; s < 4; ++s) r[4 * q + s] = v[s];
  }
  return r;
}

__device__ __forceinline__ void pack_store(char* buf, int jr, int colb, int l,
                                           f32x16 a, bool relu) {
  int rb = colb * 2 + ((l >> 5) << 3);
  int sw = (jr & 7) << 4;
#pragma unroll
  for (int q = 0; q < 4; ++q) {
    float v0 = a[4*q], v1 = a[4*q+1], v2 = a[4*q+2], v3 = a[4*q+3];
    if (relu) {
      v0 = fmaxf(v0, 0.f); v1 = fmaxf(v1, 0.f);
      v2 = fmaxf(v2, 0.f); v3 = fmaxf(v3, 0.f);
    }
    u32x2 wv; wv[0] = pk2(v0, v1); wv[1] = pk2(v2, v3);
    *(u32x2*)(buf + jr * 128 + ((rb + 16 * q) ^ sw)) = wv;
  }
}

#define MM2(accv, ahi, alo, bp) { short8 bb_ = *(bp); \
  accv = __builtin_amdgcn_mfma_f32_32x32x16_bf16(ahi, bb_, accv, 0, 0, 0); \
  accv = __builtin_amdgcn_mfma_f32_32x32x16_bf16(alo, bb_, accv, 0, 0, 0); }

#define BPTR(buf, jr, kc) ((const short8*)((buf) + (jr) * 128 + ((((kc) * 32) + kbl) ^ swz)))

__global__ __launch_bounds__(256, 3) void main_kernel(
    const float* __restrict__ pos, const float* __restrict__ qkv,
    const unsigned short* __restrict__ fW1, const unsigned short* __restrict__ fW2,
    const unsigned short* __restrict__ fA1, const unsigned short* __restrict__ fA2,
    const float* __restrict__ pb1, const float* __restrict__ pb2,
    const float* __restrict__ ab1, const float* __restrict__ ab2,
    float* __restrict__ out) {
  __shared__ char bufA[16384];  // X1 then U : [128 j][64 k] bf16, swizzled
  __shared__ char bufB[16384];  // H1 then H2c
  const int i = blockIdx.x, bt = blockIdx.y;
  const int tid = threadIdx.x;
  const int w = tid >> 6, l = tid & 63;
  const int wm = w >> 1, wn = w & 1;
  const int colb = wm * 32;
  const int jr0 = wn * 64 + (l & 31);
  const int jr1 = jr0 + 32;
  const int kbl = (l >> 5) << 4;
  const int swz = (l & 7) << 4;   // == (jr&7)<<4 for both jr0 and jr1

  // zero bufA (covers k=34..47 pad of X1)
  f32x4 z4 = {0.f, 0.f, 0.f, 0.f};
#pragma unroll
  for (int o = 0; o < 4; ++o) *(f32x4*)(bufA + tid * 16 + o * 4096) = z4;
  __syncthreads();

  // X1[j][f] = p[bt,i,f] - p[bt,j,f], f = c*17 + jj (34 features)
  for (int it = 0; it < 17; ++it) {
    int idx = tid + it * 256;
    int f = idx >> 7, j = idx & 127;
    int c = (f >= 17) ? 1 : 0;
    int jj = f - 17 * c;
    const float* ps = pos + (((bt * 17 + jj) * 3 + c) << 7);
    float val = ps[i] - ps[j];
    *(unsigned short*)(bufA + j * 128 + ((2 * f) ^ ((j & 7) << 4))) = f2bf(val);
  }
  __syncthreads();

  // ---- G1: H1^T = relu(W1 @ X1^T + b1) -> bufB (K eff = 48 >= 34) ----
  {
    f32x16 a0 = ld16(pb1 + colb, l), a1 = a0;
#pragma unroll
    for (int kc = 0; kc < 3; ++kc) {
      int fo = ((wm * 4 + kc) * 64 + l) * 8;
      short8 ahi = *(const short8*)(fW1 + fo);
      short8 alo = *(const short8*)(fW1 + 4096 + fo);
      MM2(a0, ahi, alo, BPTR(bufA, jr0, kc));
      MM2(a1, ahi, alo, BPTR(bufA, jr1, kc));
    }
    pack_store(bufB, jr0, colb, l, a0, true);
    pack_store(bufB, jr1, colb, l, a1, true);
  }
  __syncthreads();

  // ---- G2: E^T = W2 @ H1^T + b2 (stays in regs) ----
  f32x16 e0 = ld16(pb2 + colb, l), e1 = e0;
#pragma unroll
  for (int kc = 0; kc < 4; ++kc) {
    int fo = ((wm * 4 + kc) * 64 + l) * 8;
    short8 ahi = *(const short8*)(fW2 + fo);
    short8 alo = *(const short8*)(fW2 + 4096 + fo);
    MM2(e0, ahi, alo, BPTR(bufB, jr0, kc));
    MM2(e1, ahi, alo, BPTR(bufB, jr1, kc));
  }

  // ---- E-stage: U = q_i - k_j + E -> bufA ; Vp = v_j + E (regs) ----
  f32x16 vp0, vp1;
  {
    const float* qp = qkv + (bt * 128 + i) * 192 + colb;
    f32x16 qv = ld16(qp, l);
    {
      const float* rp = qkv + (bt * 128 + jr0) * 192 + colb;
      f32x16 kk = ld16(rp + 64, l), vv = ld16(rp + 128, l);
      f32x16 u;
#pragma unroll
      for (int r = 0; r < 16; ++r) { u[r] = qv[r] - kk[r] + e0[r]; vp0[r] = vv[r] + e0[r]; }
      pack_store(bufA, jr0, colb, l, u, false);
    }
    {
      const float* rp = qkv + (bt * 128 + jr1) * 192 + colb;
      f32x16 kk = ld16(rp + 64, l), vv = ld16(rp + 128, l);
      f32x16 u;
#pragma unroll
      for (int r = 0; r < 16; ++r) { u[r] = qv[r] - kk[r] + e1[r]; vp1[r] = vv[r] + e1[r]; }
      pack_store(bufA, jr1, colb, l, u, false);
    }
  }
  __syncthreads();

  // ---- G3/G4 over 4 h-chunks of 64; s = S^T[d][j] ----
  f32x16 s0 = ld16(ab2 + colb, l), s1 = s0;
  for (int hc = 0; hc < 4; ++hc) {
    f32x16 h0 = ld16(ab1 + hc * 64 + colb, l), h1 = h0;
#pragma unroll
    for (int kc = 0; kc < 4; ++kc) {
      int fo = (((hc * 2 + wm) * 4 + kc) * 64 + l) * 8;
      short8 ahi = *(const short8*)(fA1 + fo);
      short8 alo = *(const short8*)(fA1 + 16384 + fo);
      MM2(h0, ahi, alo, BPTR(bufA, jr0, kc));
      MM2(h1, ahi, alo, BPTR(bufA, jr1, kc));
    }
    pack_store(bufB, jr0, colb, l, h0, true);  // safe: prev G4 reads gated by loop-end sync
    pack_store(bufB, jr1, colb, l, h1, true);
    __syncthreads();
#pragma unroll
    for (int kc = 0; kc < 4; ++kc) {
      int fo = ((wm * 16 + hc * 4 + kc) * 64 + l) * 8;
      short8 ahi = *(const short8*)(fA2 + fo);
      short8 alo = *(const short8*)(fA2 + 16384 + fo);
      MM2(s0, ahi, alo, BPTR(bufB, jr0, kc));
      MM2(s1, ahi, alo, BPTR(bufB, jr1, kc));
    }
    __syncthreads();
  }

  // ---- epilogue: softmax over j (no max-sub; |sim| < ~12 => exp-safe in f32) ----
  float* red = (float*)bufA;  // pd[2][64], pn[2][64]
#pragma unroll
  for (int r = 0; r < 16; ++r) {
    float x0 = __expf(s0[r]);
    float x1 = __expf(s1[r]);
    float pd = x0 + x1;
    float pn = x0 * vp0[r] + x1 * vp1[r];
#pragma unroll
    for (int m = 1; m <= 16; m <<= 1) {
      pd += __shfl_xor(pd, m);
      pn += __shfl_xor(pn, m);
    }
    if ((l & 31) == 0) {
      int d = colb + (r & 3) + 8 * (r >> 2) + ((l >> 5) << 2);
      red[wn * 64 + d] = pd;
      red[128 + wn * 64 + d] = pn;
    }
  }
  __syncthreads();
  if (tid < 64) {
    float den = red[tid] + red[64 + tid];
    float num = red[128 + tid] + red[192 + tid];
    out[(bt * 128 + i) * 64 + tid] = num / den;
  }
}

extern "C" void kernel_launch(void* const* d_in, const int* in_sizes, int n_in,
                              void* d_out, int out_size, void* d_ws, size_t ws_size,
                              hipStream_t stream) {
  const float* x    = (const float*)d_in[0];
  const float* pos  = (const float*)d_in[1];
  const float* wqkv = (const float*)d_in[2];
  const float* pw1  = (const float*)d_in[3];
  const float* pb1  = (const float*)d_in[4];
  const float* pw2  = (const float*)d_in[5];
  const float* pb2  = (const float*)d_in[6];
  const float* aw1  = (const float*)d_in[7];
  const float* ab1  = (const float*)d_in[8];
  const float* aw2  = (const float*)d_in[9];
  const float* ab2  = (const float*)d_in[10];
  float* out = (float*)d_out;
  char* ws = (char*)d_ws;

  float* qkv = (float*)ws;                               // 3145728 B
  float* wT  = (float*)(ws + 3145728);                   // 49152 B
  unsigned short* fW1 = (unsigned short*)(ws + 3194880); // 16384 B
  unsigned short* fW2 = (unsigned short*)(ws + 3211264); // 16384 B
  unsigned short* fA1 = (unsigned short*)(ws + 3227648); // 65536 B
  unsigned short* fA2 = (unsigned short*)(ws + 3293184); // 65536 B

  hipLaunchKernelGGL(prep_kernel, dim3(208), dim3(256), 0, stream,
                     wqkv, pw1, pw2, aw1, aw2, wT, fW1, fW2, fA1, fA2);
  hipLaunchKernelGGL(qkv_kernel, dim3(4096), dim3(192), 0, stream, x, wT, qkv);
  hipLaunchKernelGGL(main_kernel, dim3(128, 32), dim3(256), 0, stream,
                     pos, qkv, fW1, fW2, fA1, fA2, pb1, pb2, ab1, ab2, out);
}

// Round 4
// 227.938 us; speedup vs baseline: 1.0857x; 1.0259x over previous
//
#include <hip/hip_runtime.h>

// PointTransformerLayer fused kernel for MI355X (gfx950) — round 3 (resubmit;
// round-3 bench was an infra failure: container acquisition, no counters).
// Changes vs r2: fragment-linear LDS for all activations (conflict-free
// ds_read_b128), quad-scatter b64 producer writes, vp packed to bf16 (kills
// register spills: r2 showed 3MB/dispatch scratch traffic), 4 blocks/CU,
// prep+qkv fused into one aux kernel (no wT), zero-init merged into X1 fill.
// Pipeline per (bt,i) workgroup (256 thr = 4 waves, wave = (wm m-half, wn j-half)):
//   X1[48f][128j] frags  (f>=34 zero-padded)   -> bufA
//   H1 = relu(W1 @ X1^T + b1)                  -> bufB frags
//   E  = W2 @ H1^T + b2 (regs); U = q_i-k_j+E  -> bufA frags; vp = v_j+E (bf16 regs)
//   per hc(4): H2c = relu(A1c @ U^T + b1c) -> bufB frags ; S += A2c @ H2c^T
//   softmax over j + weighted vp sum (shuffle reduce, cross-wave via LDS)
// Weights hi/lo bf16 split (2 MFMA/product), activations single bf16.
// ws: qkv f32 @0 (3145728 B); fW1@3145728 (12288 B); fW2@3158016 (16384 B);
//     fA1@3174400 (65536 B); fA2@3239936 (65536 B); end 3305472 B.

typedef short short8 __attribute__((ext_vector_type(8)));
typedef float f32x4 __attribute__((ext_vector_type(4)));
typedef float f32x16 __attribute__((ext_vector_type(16)));
typedef unsigned int u32x2 __attribute__((ext_vector_type(2)));

__device__ __forceinline__ unsigned short f2bf(float x) {
  union { float f; unsigned int u; } a; a.f = x;
  unsigned int r = a.u + 0x7fffu + ((a.u >> 16) & 1u);  // RNE
  return (unsigned short)(r >> 16);
}
__device__ __forceinline__ float bf2f(unsigned short h) {
  union { unsigned int u; float f; } a; a.u = ((unsigned int)h) << 16; return a.f;
}
__device__ __forceinline__ unsigned int pk2(float a, float b) {  // a->lo16, b->hi16
  unsigned int r;
  asm("v_cvt_pk_bf16_f32 %0, %1, %2" : "=v"(r) : "v"(a), "v"(b));
  return r;
}

// ---------------- aux: weight A-frags (hi/lo) + qkv GEMM ----------------
// A-frag (32x32x16): lane l holds A[row = mt*32 + (l&31)][k = kc*16 + (l>>5)*8 + e].
// linear: idx = ((mt*KC + kc)*64 + lane)*8 + e ; hi plane then lo plane (shorts).
__device__ __forceinline__ void fill_frag(unsigned short* dst, int plane,
    const float* src, int Ksrc, int KC, int idx) {
  int e = idx & 7;
  int lane = (idx >> 3) & 63;
  int kc = (idx >> 9) % KC;
  int mt = idx / (512 * KC);
  int row = mt * 32 + (lane & 31);
  int k = kc * 16 + ((lane >> 5) << 3) + e;
  float v = (k < Ksrc) ? src[row * Ksrc + k] : 0.0f;
  unsigned short hi = f2bf(v);
  unsigned short lo = f2bf(v - bf2f(hi));
  dst[idx] = hi;
  dst[plane + idx] = lo;
}

#define PREP_BLOCKS 156  // 39936 threads == 3072+4096+16384+16384 frag elems

__global__ void aux_kernel(const float* __restrict__ wqkv,
    const float* __restrict__ pw1, const float* __restrict__ pw2,
    const float* __restrict__ aw1, const float* __restrict__ aw2,
    const float* __restrict__ x,
    unsigned short* __restrict__ fW1, unsigned short* __restrict__ fW2,
    unsigned short* __restrict__ fA1, unsigned short* __restrict__ fA2,
    float* __restrict__ qkv) {
  if (blockIdx.x >= PREP_BLOCKS) {  // ---- qkv path: row = bt*128+n ----
    __shared__ float xs[64];
    int row = blockIdx.x - PREP_BLOCKS;
    int tid = threadIdx.x;
    if (tid < 64) xs[tid] = x[row * 64 + tid];
    __syncthreads();
    if (tid < 192) {
      const float* wr = wqkv + tid * 64;  // row of w_qkv (contiguous, vectorizes)
      float acc = 0.f;
#pragma unroll
      for (int k = 0; k < 64; ++k) acc += xs[k] * wr[k];
      qkv[row * 192 + tid] = acc;
    }
    return;
  }
  int gid = blockIdx.x * 256 + threadIdx.x;
  if (gid < 3072) { fill_frag(fW1, 3072, pw1, 34, 3, gid); return; }    // [64][34->48]
  gid -= 3072;
  if (gid < 4096) { fill_frag(fW2, 4096, pw2, 64, 4, gid); return; }    // [64][64]
  gid -= 4096;
  if (gid < 16384) { fill_frag(fA1, 16384, aw1, 64, 4, gid); return; }  // [256][64]
  gid -= 16384;
  fill_frag(fA2, 16384, aw2, 256, 16, gid);                             // [64][256]
}

// ---------------- main fused kernel ----------------
// C/D layout 32x32: col = l&31, row = (reg&3) + 8*(reg>>2) + 4*(l>>5).
__device__ __forceinline__ f32x16 ld16(const float* p, int l) {
  f32x16 r;
#pragma unroll
  for (int q = 0; q < 4; ++q) {
    f32x4 v = *(const f32x4*)(p + 8 * q + ((l >> 5) << 2));
#pragma unroll
    for (int s = 0; s < 4; ++s) r[4 * q + s] = v[s];
  }
  return r;
}

// scatter C-tile (32 rows starting at kcb*16) into B-frag-linear LDS
__device__ __forceinline__ void scat(char* buf, int jt, int lc, int lh, int kcb,
                                     f32x16 a, bool relu) {
#pragma unroll
  for (int q = 0; q < 4; ++q) {
    float v0 = a[4*q], v1 = a[4*q+1], v2 = a[4*q+2], v3 = a[4*q+3];
    if (relu) {
      v0 = fmaxf(v0, 0.f); v1 = fmaxf(v1, 0.f);
      v2 = fmaxf(v2, 0.f); v3 = fmaxf(v3, 0.f);
    }
    u32x2 wv; wv[0] = pk2(v0, v1); wv[1] = pk2(v2, v3);
    int kc = kcb + (q >> 1);
    *(u32x2*)(buf + ((kc * 4 + jt) << 10) + (((q & 1) << 5) + lc) * 16 + lh * 8) = wv;
  }
}

#define MFMA32(acc, av, bv) \
  acc = __builtin_amdgcn_mfma_f32_32x32x16_bf16(av, bv, acc, 0, 0, 0)

__global__ __launch_bounds__(256, 4) void main_kernel(
    const float* __restrict__ pos, const float* __restrict__ qkv,
    const unsigned short* __restrict__ fW1, const unsigned short* __restrict__ fW2,
    const unsigned short* __restrict__ fA1, const unsigned short* __restrict__ fA2,
    const float* __restrict__ pb1, const float* __restrict__ pb2,
    const float* __restrict__ ab1, const float* __restrict__ ab2,
    float* __restrict__ out) {
  __shared__ char bufA[16384];  // X1 (kc0..2) then U (kc0..3), frag-linear
  __shared__ char bufB[16384];  // H1 then H2c, frag-linear
  const int i = blockIdx.x, bt = blockIdx.y;
  const int tid = threadIdx.x;
  const int w = tid >> 6, l = tid & 63;
  const int wm = w >> 1, wn = w & 1;
  const int lc = l & 31, lh = l >> 5;

  // ---- X1 frags: f = c*17+jj (34 real features, 48 with zero pad) ----
#pragma unroll
  for (int it = 0; it < 24; ++it) {
    int idx = tid + (it << 8);
    int f = idx >> 7, j = idx & 127;
    float val = 0.f;
    if (f < 34) {
      int c = (f >= 17) ? 1 : 0;
      int jj = f - 17 * c;
      const float* ps = pos + (((bt * 17 + jj) * 3 + c) << 7);
      val = ps[i] - ps[j];
    }
    int kc = f >> 4, lane = ((f >> 3) & 1) * 32 + (j & 31), jt = j >> 5, e = f & 7;
    *(unsigned short*)(bufA + ((kc * 4 + jt) << 10) + lane * 16 + e * 2) = f2bf(val);
  }
  __syncthreads();

  // ---- G1: H1 = relu(W1 @ X1^T + b1) -> bufB frags (K=48) ----
#pragma unroll
  for (int jr = 0; jr < 2; ++jr) {
    int jt = 2 * wn + jr;
    f32x16 acc = ld16(pb1 + wm * 32, l);
#pragma unroll
    for (int kc = 0; kc < 3; ++kc) {
      const unsigned short* ap = fW1 + ((wm * 3 + kc) * 64 + l) * 8;
      short8 ahi = *(const short8*)ap;
      short8 alo = *(const short8*)(ap + 3072);
      short8 b = *(const short8*)(bufA + ((kc * 4 + jt) << 10) + l * 16);
      MFMA32(acc, ahi, b); MFMA32(acc, alo, b);
    }
    scat(bufB, jt, lc, lh, 2 * wm, acc, true);
  }
  __syncthreads();

  // ---- G2 + E-stage: E = W2 @ H1^T + b2; U -> bufA frags; vp packed bf16 ----
  unsigned int vpk0[8], vpk1[8];
  const float* qkv_bt = qkv + (size_t)(bt * 128) * 192;
  const float* qp = qkv_bt + i * 192 + wm * 32;
#pragma unroll
  for (int jr = 0; jr < 2; ++jr) {
    int jt = 2 * wn + jr;
    f32x16 e = ld16(pb2 + wm * 32, l);
#pragma unroll
    for (int kc = 0; kc < 4; ++kc) {
      const unsigned short* ap = fW2 + ((wm * 4 + kc) * 64 + l) * 8;
      short8 ahi = *(const short8*)ap;
      short8 alo = *(const short8*)(ap + 4096);
      short8 b = *(const short8*)(bufB + ((kc * 4 + jt) << 10) + l * 16);
      MFMA32(e, ahi, b); MFMA32(e, alo, b);
    }
    f32x16 qv = ld16(qp, l);
    const float* rp = qkv_bt + (jt * 32 + lc) * 192 + wm * 32;
    f32x16 kk = ld16(rp + 64, l), vv = ld16(rp + 128, l);
    f32x16 u;
#pragma unroll
    for (int r = 0; r < 16; ++r) u[r] = qv[r] - kk[r] + e[r];
#pragma unroll
    for (int s = 0; s < 8; ++s) {
      unsigned int p = pk2(vv[2*s] + e[2*s], vv[2*s+1] + e[2*s+1]);
      if (jr == 0) vpk0[s] = p; else vpk1[s] = p;
    }
    scat(bufA, jt, lc, lh, 2 * wm, u, false);
  }
  __syncthreads();

  // ---- G3/G4 over 4 h-chunks of 64; s = S^T[d][j] ----
  f32x16 s0 = ld16(ab2 + wm * 32, l), s1 = s0;
#pragma unroll 1
  for (int hc = 0; hc < 4; ++hc) {
#pragma unroll
    for (int jr = 0; jr < 2; ++jr) {  // G3: H2c = relu(A1c @ U^T + b1c)
      int jt = 2 * wn + jr;
      f32x16 h = ld16(ab1 + hc * 64 + wm * 32, l);
#pragma unroll
      for (int kc = 0; kc < 4; ++kc) {
        const unsigned short* ap = fA1 + (((2 * hc + wm) * 4 + kc) * 64 + l) * 8;
        short8 ahi = *(const short8*)ap;
        short8 alo = *(const short8*)(ap + 16384);
        short8 b = *(const short8*)(bufA + ((kc * 4 + jt) << 10) + l * 16);
        MFMA32(h, ahi, b); MFMA32(h, alo, b);
      }
      scat(bufB, jt, lc, lh, 2 * wm, h, true);
    }
    __syncthreads();
    {  // G4: S += A2c @ H2c^T   (jr0 -> s0, jr1 -> s1, explicit)
      int jt = 2 * wn;
#pragma unroll
      for (int kc = 0; kc < 4; ++kc) {
        const unsigned short* ap = fA2 + ((wm * 16 + hc * 4 + kc) * 64 + l) * 8;
        short8 ahi = *(const short8*)ap;
        short8 alo = *(const short8*)(ap + 16384);
        short8 b = *(const short8*)(bufB + ((kc * 4 + jt) << 10) + l * 16);
        MFMA32(s0, ahi, b); MFMA32(s0, alo, b);
      }
      jt = 2 * wn + 1;
#pragma unroll
      for (int kc = 0; kc < 4; ++kc) {
        const unsigned short* ap = fA2 + ((wm * 16 + hc * 4 + kc) * 64 + l) * 8;
        short8 ahi = *(const short8*)ap;
        short8 alo = *(const short8*)(ap + 16384);
        short8 b = *(const short8*)(bufB + ((kc * 4 + jt) << 10) + l * 16);
        MFMA32(s1, ahi, b); MFMA32(s1, alo, b);
      }
    }
    __syncthreads();
  }

  // ---- epilogue: softmax over j (no max-sub, exp-safe) + weighted vp sum ----
  float* red = (float*)bufA;  // pd[2][64] then pn[2][64]
#pragma unroll
  for (int q = 0; q < 4; ++q) {
#pragma unroll
    for (int sp = 0; sp < 2; ++sp) {
      int r0 = 4 * q + 2 * sp;
      int pi = 2 * q + sp;
      float x00 = __expf(s0[r0]),     x10 = __expf(s1[r0]);
      float x01 = __expf(s0[r0 + 1]), x11 = __expf(s1[r0 + 1]);
      float v00 = __uint_as_float(vpk0[pi] << 16);
      float v01 = __uint_as_float(vpk0[pi] & 0xffff0000u);
      float v10 = __uint_as_float(vpk1[pi] << 16);
      float v11 = __uint_as_float(vpk1[pi] & 0xffff0000u);
      float pdA = x00 + x10, pnA = x00 * v00 + x10 * v10;
      float pdB = x01 + x11, pnB = x01 * v01 + x11 * v11;
#pragma unroll
      for (int m = 1; m <= 16; m <<= 1) {
        pdA += __shfl_xor(pdA, m); pnA += __shfl_xor(pnA, m);
        pdB += __shfl_xor(pdB, m); pnB += __shfl_xor(pnB, m);
      }
      if (lc == 0) {
        int dA = wm * 32 + (r0 & 3) + 8 * (r0 >> 2) + 4 * lh;
        red[wn * 64 + dA] = pdA;       red[128 + wn * 64 + dA] = pnA;
        red[wn * 64 + dA + 1] = pdB;   red[128 + wn * 64 + dA + 1] = pnB;
      }
    }
  }
  __syncthreads();
  if (tid < 64) {
    float den = red[tid] + red[64 + tid];
    float num = red[128 + tid] + red[192 + tid];
    out[(bt * 128 + i) * 64 + tid] = num / den;
  }
}

extern "C" void kernel_launch(void* const* d_in, const int* in_sizes, int n_in,
                              void* d_out, int out_size, void* d_ws, size_t ws_size,
                              hipStream_t stream) {
  const float* x    = (const float*)d_in[0];
  const float* pos  = (const float*)d_in[1];
  const float* wqkv = (const float*)d_in[2];
  const float* pw1  = (const float*)d_in[3];
  const float* pb1  = (const float*)d_in[4];
  const float* pw2  = (const float*)d_in[5];
  const float* pb2  = (const float*)d_in[6];
  const float* aw1  = (const float*)d_in[7];
  const float* ab1  = (const float*)d_in[8];
  const float* aw2  = (const float*)d_in[9];
  const float* ab2  = (const float*)d_in[10];
  float* out = (float*)d_out;
  char* ws = (char*)d_ws;

  float* qkv = (float*)ws;                               // 3145728 B
  unsigned short* fW1 = (unsigned short*)(ws + 3145728); // 12288 B
  unsigned short* fW2 = (unsigned short*)(ws + 3158016); // 16384 B
  unsigned short* fA1 = (unsigned short*)(ws + 3174400); // 65536 B
  unsigned short* fA2 = (unsigned short*)(ws + 3239936); // 65536 B (end 3305472)

  hipLaunchKernelGGL(aux_kernel, dim3(PREP_BLOCKS + 4096), dim3(256), 0, stream,
                     wqkv, pw1, pw2, aw1, aw2, x, fW1, fW2, fA1, fA2, qkv);
  hipLaunchKernelGGL(main_kernel, dim3(128, 32), dim3(256), 0, stream,
                     pos, qkv, fW1, fW2, fA1, fA2, pb1, pb2, ab1, ab2, out);
}